// Round 4
// baseline (215.065 us; speedup 1.0000x reference)
//
#include <hip/hip_runtime.h>

#define F_ALL 20000
#define FP    10000
#define BB    4
#define KK    16
#define OO    128
#define NFACE 40000
#define NBLK  625            // 64 faces per attn block

// workspace float offsets (~41 MB total)
#define WS_FEAT 0
#define WS_AGG  (BB*F_ALL*64)            // 5,120,000
#define WS_GP   (WS_AGG + NFACE*64)      // 7,680,000
#define WS_SAP  (WS_GP + NBLK*4096)      // 10,240,000
#define WS_MT   (WS_SAP + NBLK*64)       // 10,280,000  MT[j*64+i] = A[i][j]
#define WS_V0   (WS_MT + 4096)
#define WS_G    (WS_V0 + 64)
#define WS_SUMA (WS_G + 4096)
#define WS_SC   (WS_SUMA + 64)
#define WS_SH   (WS_SC + 128)

template<int CTRL>
__device__ __forceinline__ float dpp_add(float x) {
    return x + __int_as_float(__builtin_amdgcn_update_dpp(0, __float_as_int(x), CTRL, 0xF, 0xF, true));
}
// all-reduce sum within each 16-lane row (4 VALU DPP stages)
__device__ __forceinline__ float sum16(float x) {
    x = dpp_add<0x121>(x);
    x = dpp_add<0x122>(x);
    x = dpp_add<0x124>(x);
    x = dpp_add<0x128>(x);
    return x;
}

// ---------- K1: transpose fea -> feaT (blocks 0..1251) + precompute (1252..1267) ----------
__global__ __launch_bounds__(256) void k_pre(const float* __restrict__ fea,
                                             const float* __restrict__ Wk,
                                             const float* __restrict__ bk,
                                             const float* __restrict__ Wq,
                                             float* __restrict__ ws) {
    __shared__ float tile[64][65];
    int tid = threadIdx.x;
    if (blockIdx.x < 1252) {
        int bb = blockIdx.x / 313;
        int tb = blockIdx.x % 313;
        int fbase = tb * 64;
        int x  = tid & 63;
        int y0 = tid >> 6;
        int f = fbase + x;
        float* feaT = ws + WS_FEAT;
        if (f < F_ALL) {
#pragma unroll
            for (int i = 0; i < 16; i++) {
                int c = y0 + i * 4;
                tile[c][x] = fea[((long)bb * 64 + c) * F_ALL + f];
            }
        }
        __syncthreads();
#pragma unroll
        for (int i = 0; i < 16; i++) {
            int fr = y0 + i * 4;
            int ff = fbase + fr;
            if (ff < F_ALL)
                feaT[((long)bb * F_ALL + ff) * 64 + x] = tile[x][fr];
        }
    } else {
        int idx = (blockIdx.x - 1252) * 256 + tid;    // 0..4095
        int j = idx >> 6, i = idx & 63;
        float acc = 0.f;
#pragma unroll 8
        for (int o = 0; o < 128; o++) acc += Wq[o * 64 + i] * Wk[o * 64 + j];
        ws[WS_MT + idx] = acc;
        if (blockIdx.x == 1252 && tid < 64) {
            float a = 0.f;
            for (int o = 0; o < 128; o++) a += Wq[o * 64 + tid] * bk[o];
            ws[WS_V0 + tid] = a;
        }
    }
}

// ---------- K2: fused qvec + attention + gram partial (64 faces / block) ----------
__global__ __launch_bounds__(256) void k_attn(const int* __restrict__ ring,
                                              const int* __restrict__ pool,
                                              float* __restrict__ ws) {
    __shared__ __align__(16) float lds[12608];   // 50.4 KB
    float* At = lds;                 // [4096]  A^T; aliased by Ag after phase 2
    float* Sf = lds + 4096;          // [64*65] self rows
    float* U  = lds + 8256;          // [64*68] query vectors
    int tid = threadIdx.x;
    int fbase = blockIdx.x * 64;
    const float* feaT = ws + WS_FEAT;
    const float scale = 0.08838834764831845f;   // 1/sqrt(128)

    // phase 1: stage A^T and gathered self rows
    for (int i = tid; i < 4096; i += 256) At[i] = ws[WS_MT + i];
    {
        int r = tid >> 2;
        int face = fbase + r;
        int b = face / FP;
        int p = pool[face - b * FP];
        const float* src = feaT + ((long)(b * F_ALL + p)) * 64;
        int off = (tid & 3) * 4;
#pragma unroll
        for (int it = 0; it < 4; it++, off += 16) {
            float4 v = *(const float4*)(src + off);
            Sf[r * 65 + off + 0] = v.x;
            Sf[r * 65 + off + 1] = v.y;
            Sf[r * 65 + off + 2] = v.z;
            Sf[r * 65 + off + 3] = v.w;
        }
    }
    __syncthreads();

    // phase 2: U = Sf * A + v0
    int ti = tid & 15, tj = tid >> 4;
    {
        int f0 = ti * 4, o0 = tj * 4;
        float4 v0 = *(const float4*)&ws[WS_V0 + o0];
        float acc[4][4];
#pragma unroll
        for (int a = 0; a < 4; a++) {
            acc[a][0] = v0.x; acc[a][1] = v0.y; acc[a][2] = v0.z; acc[a][3] = v0.w;
        }
        for (int j = 0; j < 64; j++) {
            float4 wv = *(const float4*)&At[j * 64 + o0];
#pragma unroll
            for (int a = 0; a < 4; a++) {
                float av = Sf[(f0 + a) * 65 + j];
                acc[a][0] += av * wv.x;
                acc[a][1] += av * wv.y;
                acc[a][2] += av * wv.z;
                acc[a][3] += av * wv.w;
            }
        }
#pragma unroll
        for (int a = 0; a < 4; a++)
            *(float4*)&U[(f0 + a) * 68 + o0] =
                make_float4(acc[a][0], acc[a][1], acc[a][2], acc[a][3]);
    }
    __syncthreads();

    // phase 3: attention (wave = 4 faces, 4 iterations); Ag aliases At (dead)
    float* Ag = At;
    int lane = tid & 63;
    int il = lane & 15, c4 = il * 4;
    for (int it = 0; it < 4; it++) {
        int fl = (tid >> 4) + it * 16;
        int face = fbase + fl;
        int b = face / FP;
        const float* fb = feaT + ((long)b * F_ALL) * 64 + c4;

        float4 sf = make_float4(Sf[fl * 65 + c4], Sf[fl * 65 + c4 + 1],
                                Sf[fl * 65 + c4 + 2], Sf[fl * 65 + c4 + 3]);
        float4 u = *(const float4*)&U[fl * 68 + c4];

        int rv = ring[face * KK + il];
        float4 nv[KK];
#pragma unroll
        for (int k = 0; k < KK; k++) {
            int rk = __shfl(rv, (lane & 48) | k, 64);
            nv[k] = *(const float4*)(fb + (long)rk * 64);
        }

        float l[KK + 1];
        l[0] = sum16(u.x * sf.x + u.y * sf.y + u.z * sf.z + u.w * sf.w) * scale;
#pragma unroll
        for (int k = 0; k < KK; k++)
            l[k + 1] = sum16(u.x * nv[k].x + u.y * nv[k].y + u.z * nv[k].z + u.w * nv[k].w) * scale;

        float m = l[0];
#pragma unroll
        for (int k = 1; k <= KK; k++) m = fmaxf(m, l[k]);
        float den = 0.f;
#pragma unroll
        for (int k = 0; k <= KK; k++) { l[k] = __expf(l[k] - m); den += l[k]; }
        float inv = 1.0f / den;

        float4 a;
        a.x = l[0] * sf.x; a.y = l[0] * sf.y; a.z = l[0] * sf.z; a.w = l[0] * sf.w;
#pragma unroll
        for (int k = 0; k < KK; k++) {
            a.x += l[k + 1] * nv[k].x;
            a.y += l[k + 1] * nv[k].y;
            a.z += l[k + 1] * nv[k].z;
            a.w += l[k + 1] * nv[k].w;
        }
        a.x *= inv; a.y *= inv; a.z *= inv; a.w *= inv;
        *(float4*)&Ag[fl * 64 + c4] = a;
        *(float4*)&ws[WS_AGG + (long)face * 64 + c4] = a;
    }
    __syncthreads();

    // phase 4: per-block gram partial over the 64 faces in LDS
    float acc[4][4];
#pragma unroll
    for (int a = 0; a < 4; a++)
#pragma unroll
        for (int b = 0; b < 4; b++) acc[a][b] = 0.f;
    float gacc[4] = {0.f, 0.f, 0.f, 0.f};
#pragma unroll 4
    for (int f = 0; f < 64; f++) {
        float4 av = *(const float4*)&Ag[f * 64 + ti * 4];
        float4 bv = *(const float4*)&Ag[f * 64 + tj * 4];
        float avv[4] = {av.x, av.y, av.z, av.w};
        float bvv[4] = {bv.x, bv.y, bv.z, bv.w};
#pragma unroll
        for (int a = 0; a < 4; a++) {
#pragma unroll
            for (int b = 0; b < 4; b++) acc[a][b] += avv[a] * bvv[b];
            gacc[a] += avv[a];
        }
    }
    float* gp = ws + WS_GP;
#pragma unroll
    for (int a = 0; a < 4; a++)
        *(float4*)&gp[(long)blockIdx.x * 4096 + (ti * 4 + a) * 64 + tj * 4] =
            make_float4(acc[a][0], acc[a][1], acc[a][2], acc[a][3]);
    if (tj == 0)
        *(float4*)&ws[WS_SAP + blockIdx.x * 64 + ti * 4] =
            make_float4(gacc[0], gacc[1], gacc[2], gacc[3]);
}

// ---------- K3: reduce gram partials (64 blocks for G, 1 for sumA) ----------
__global__ __launch_bounds__(256) void k_gsum(float* __restrict__ ws) {
    __shared__ float red[256];
    const float* gp  = ws + WS_GP;
    const float* sap = ws + WS_SAP;
    int t = threadIdx.x;
    int e = t & 63, pc = t >> 6;
    int p0 = pc * 157;
    int p1 = p0 + 157; if (p1 > NBLK) p1 = NBLK;
    if (blockIdx.x < 64) {
        int eg = blockIdx.x * 64 + e;
        float s = 0.f;
        for (int p = p0; p < p1; p++) s += gp[(long)p * 4096 + eg];
        red[t] = s;
        __syncthreads();
        if (pc == 0) ws[WS_G + eg] = red[e] + red[e + 64] + red[e + 128] + red[e + 192];
    } else {
        float s = 0.f;
        for (int p = p0; p < p1; p++) s += sap[p * 64 + e];
        red[t] = s;
        __syncthreads();
        if (pc == 0) ws[WS_SUMA + e] = red[e] + red[e + 64] + red[e + 128] + red[e + 192];
    }
}

// ---------- K4: BN stats -> per-o scale/shift ----------
__global__ __launch_bounds__(256) void k_stats(const float* __restrict__ Wc,
                                               const float* __restrict__ bc,
                                               const float* __restrict__ gamma,
                                               const float* __restrict__ beta,
                                               float* __restrict__ ws) {
    __shared__ float Gs[4096];
    __shared__ float gs[64];
    __shared__ float qs[256];
    int tid = threadIdx.x;
    for (int i = tid; i < 4096; i += 256) Gs[i] = ws[WS_G + i];
    if (tid < 64) gs[tid] = ws[WS_SUMA + tid];
    __syncthreads();

    int o = tid & 127, h = tid >> 7;
    float w[64];
#pragma unroll
    for (int q = 0; q < 16; q++) {
        float4 t = *(const float4*)&Wc[o * 64 + q * 4];
        w[q * 4 + 0] = t.x; w[q * 4 + 1] = t.y; w[q * 4 + 2] = t.z; w[q * 4 + 3] = t.w;
    }
    float qp = 0.f;
    for (int i = h * 32; i < h * 32 + 32; i++) {
        float t = 0.f;
#pragma unroll
        for (int j = 0; j < 64; j++) t += Gs[i * 64 + j] * w[j];
        qp += Wc[o * 64 + i] * t;
    }
    qs[tid] = qp;
    __syncthreads();
    if (h == 0) {
        const float invN = 1.0f / (float)NFACE;
        float qform = qs[o] + qs[o + 128];
        float md = 0.f;
#pragma unroll
        for (int j = 0; j < 64; j++) md += gs[j] * w[j];
        float bco = bc[o];
        float mean = md * invN + bco;
        float ey2  = (qform + 2.f * bco * md) * invN + bco * bco;
        float var  = ey2 - mean * mean;
        float sc   = gamma[o] * rsqrtf(var + 1e-5f);
        ws[WS_SC + o] = sc;
        ws[WS_SH + o] = beta[o] + (bco - mean) * sc;
    }
}

// ---------- K5: out = relu((Wc*agg)*sc + sh)  [B,O,Fp] ----------
__global__ __launch_bounds__(256) void k_out(const float* __restrict__ Wc,
                                             const float* __restrict__ ws,
                                             float* __restrict__ out) {
    __shared__ __align__(16) float WcT[64 * 132];   // [j][o]
    __shared__ __align__(16) float AgT[64 * 68];    // [j][f]
    const float* agg = ws + WS_AGG;
    int tid = threadIdx.x;
    int fbase = blockIdx.x * 64;
    for (int i = tid; i < 128 * 64; i += 256) {
        int o = i >> 6, j = i & 63;
        WcT[j * 132 + o] = Wc[i];
    }
    for (int i = tid; i < 64 * 64; i += 256) {
        int f = i >> 6, j = i & 63;
        AgT[j * 68 + f] = agg[((long)(fbase + f)) * 64 + j];
    }
    __syncthreads();

    int tx = tid & 15, ty = tid >> 4;   // tx: 4 faces, ty: 8 outputs
    float acc[8][4];
#pragma unroll
    for (int a = 0; a < 8; a++)
#pragma unroll
        for (int b = 0; b < 4; b++) acc[a][b] = 0.f;

    for (int j = 0; j < 64; j++) {
        float4 w0 = *(const float4*)&WcT[j * 132 + ty * 8];
        float4 w1 = *(const float4*)&WcT[j * 132 + ty * 8 + 4];
        float4 a0 = *(const float4*)&AgT[j * 68 + tx * 4];
        float wv[8] = {w0.x, w0.y, w0.z, w0.w, w1.x, w1.y, w1.z, w1.w};
        float av[4] = {a0.x, a0.y, a0.z, a0.w};
#pragma unroll
        for (int oi = 0; oi < 8; oi++)
#pragma unroll
            for (int fi = 0; fi < 4; fi++) acc[oi][fi] += wv[oi] * av[fi];
    }

    int fg0 = fbase + tx * 4;
    int b   = fg0 / FP;
    int fp0 = fg0 - b * FP;
#pragma unroll
    for (int oi = 0; oi < 8; oi++) {
        int o = ty * 8 + oi;
        float sc = ws[WS_SC + o];
        float sh = ws[WS_SH + o];
        float4 v;
        v.x = fmaxf(acc[oi][0] * sc + sh, 0.f);
        v.y = fmaxf(acc[oi][1] * sc + sh, 0.f);
        v.z = fmaxf(acc[oi][2] * sc + sh, 0.f);
        v.w = fmaxf(acc[oi][3] * sc + sh, 0.f);
        *(float4*)&out[((long)(b * OO + o)) * FP + fp0] = v;
    }
}

extern "C" void kernel_launch(void* const* d_in, const int* in_sizes, int n_in,
                              void* d_out, int out_size, void* d_ws, size_t ws_size,
                              hipStream_t stream) {
    const float* fea  = (const float*)d_in[0];
    const int*   ring = (const int*)d_in[1];
    const int*   pool = (const int*)d_in[2];
    const float* Wk = (const float*)d_in[4];
    const float* bk = (const float*)d_in[5];
    const float* Wq = (const float*)d_in[6];
    // bq unused: its logit contribution is constant per face -> cancels in softmax
    const float* Wc = (const float*)d_in[8];
    const float* bc = (const float*)d_in[9];
    const float* gamma = (const float*)d_in[10];
    const float* beta  = (const float*)d_in[11];

    float* out = (float*)d_out;
    float* ws  = (float*)d_ws;

    k_pre  <<<1268, 256, 0, stream>>>(fea, Wk, bk, Wq, ws);
    k_attn <<<NBLK, 256, 0, stream>>>(ring, pool, ws);
    k_gsum <<<65,   256, 0, stream>>>(ws);
    k_stats<<<1,    256, 0, stream>>>(Wc, bc, gamma, beta, ws);
    k_out  <<<NBLK, 256, 0, stream>>>(Wc, ws, out);
}

// Round 5
// 173.791 us; speedup vs baseline: 1.2375x; 1.2375x over previous
//
#include <hip/hip_runtime.h>

#define F_ALL 20000
#define FP    10000
#define BB    4
#define KK    16
#define OO    128
#define NFACE 40000
#define NBLK  625            // 64 faces per attn block

// workspace float offsets (~41 MB total)
#define WS_FEAT 0
#define WS_AGG  (BB*F_ALL*64)            // 5,120,000
#define WS_GP   (WS_AGG + NFACE*64)      // 7,680,000
#define WS_SAP  (WS_GP + NBLK*4096)      // 10,240,000
#define WS_MT   (WS_SAP + NBLK*64)       // 10,280,000  MT[j*64+i] = A[i][j]
#define WS_V0   (WS_MT + 4096)
#define WS_G    (WS_V0 + 64)
#define WS_SUMA (WS_G + 4096)
#define WS_SC   (WS_SUMA + 64)
#define WS_SH   (WS_SC + 128)

template<int CTRL>
__device__ __forceinline__ float dpp_add(float x) {
    return x + __int_as_float(__builtin_amdgcn_update_dpp(0, __float_as_int(x), CTRL, 0xF, 0xF, true));
}
// all-reduce sum within each 16-lane row (4 VALU DPP stages)
__device__ __forceinline__ float sum16(float x) {
    x = dpp_add<0x121>(x);
    x = dpp_add<0x122>(x);
    x = dpp_add<0x124>(x);
    x = dpp_add<0x128>(x);
    return x;
}

// ---------- K1: transpose fea -> feaT (blocks 0..1251) + precompute (1252..1267) ----------
__global__ __launch_bounds__(256) void k_pre(const float* __restrict__ fea,
                                             const float* __restrict__ Wk,
                                             const float* __restrict__ bk,
                                             const float* __restrict__ Wq,
                                             float* __restrict__ ws) {
    __shared__ float tile[64][65];
    int tid = threadIdx.x;
    if (blockIdx.x < 1252) {
        int bb = blockIdx.x / 313;
        int tb = blockIdx.x % 313;
        int fbase = tb * 64;
        int x  = tid & 63;
        int y0 = tid >> 6;
        int f = fbase + x;
        float* feaT = ws + WS_FEAT;
        if (f < F_ALL) {
#pragma unroll
            for (int i = 0; i < 16; i++) {
                int c = y0 + i * 4;
                tile[c][x] = fea[((long)bb * 64 + c) * F_ALL + f];
            }
        }
        __syncthreads();
#pragma unroll
        for (int i = 0; i < 16; i++) {
            int fr = y0 + i * 4;
            int ff = fbase + fr;
            if (ff < F_ALL)
                feaT[((long)bb * F_ALL + ff) * 64 + x] = tile[x][fr];
        }
    } else {
        int idx = (blockIdx.x - 1252) * 256 + tid;    // 0..4095
        int j = idx >> 6, i = idx & 63;
        float acc = 0.f;
#pragma unroll 8
        for (int o = 0; o < 128; o++) acc += Wq[o * 64 + i] * Wk[o * 64 + j];
        ws[WS_MT + idx] = acc;
        if (blockIdx.x == 1252 && tid < 64) {
            float a = 0.f;
            for (int o = 0; o < 128; o++) a += Wq[o * 64 + tid] * bk[o];
            ws[WS_V0 + tid] = a;
            ws[WS_SUMA + tid] = 0.f;      // zero for k_gsum atomics (ws re-poisoned)
        }
    }
}

// ---------- K2: fused qvec + attention + gram partial (64 faces / block) ----------
__global__ __launch_bounds__(256) void k_attn(const int* __restrict__ ring,
                                              const int* __restrict__ pool,
                                              float* __restrict__ ws) {
    __shared__ __align__(16) float lds[12608];   // 50.4 KB
    float* At = lds;                 // [4096]  A^T; aliased by Ag after phase 2
    float* Sf = lds + 4096;          // [64*65] self rows
    float* U  = lds + 8256;          // [64*68] query vectors
    int tid = threadIdx.x;
    int fbase = blockIdx.x * 64;
    const float* feaT = ws + WS_FEAT;
    const float scale = 0.08838834764831845f;   // 1/sqrt(128)

    // phase 1: stage A^T and gathered self rows
    for (int i = tid; i < 4096; i += 256) At[i] = ws[WS_MT + i];
    {
        int r = tid >> 2;
        int face = fbase + r;
        int b = face / FP;
        int p = pool[face - b * FP];
        const float* src = feaT + ((long)(b * F_ALL + p)) * 64;
        int off = (tid & 3) * 4;
#pragma unroll
        for (int it = 0; it < 4; it++, off += 16) {
            float4 v = *(const float4*)(src + off);
            Sf[r * 65 + off + 0] = v.x;
            Sf[r * 65 + off + 1] = v.y;
            Sf[r * 65 + off + 2] = v.z;
            Sf[r * 65 + off + 3] = v.w;
        }
    }
    __syncthreads();

    // phase 2: U = Sf * A + v0
    int ti = tid & 15, tj = tid >> 4;
    {
        int f0 = ti * 4, o0 = tj * 4;
        float4 v0 = *(const float4*)&ws[WS_V0 + o0];
        float acc[4][4];
#pragma unroll
        for (int a = 0; a < 4; a++) {
            acc[a][0] = v0.x; acc[a][1] = v0.y; acc[a][2] = v0.z; acc[a][3] = v0.w;
        }
        for (int j = 0; j < 64; j++) {
            float4 wv = *(const float4*)&At[j * 64 + o0];
#pragma unroll
            for (int a = 0; a < 4; a++) {
                float av = Sf[(f0 + a) * 65 + j];
                acc[a][0] += av * wv.x;
                acc[a][1] += av * wv.y;
                acc[a][2] += av * wv.z;
                acc[a][3] += av * wv.w;
            }
        }
#pragma unroll
        for (int a = 0; a < 4; a++)
            *(float4*)&U[(f0 + a) * 68 + o0] =
                make_float4(acc[a][0], acc[a][1], acc[a][2], acc[a][3]);
    }
    __syncthreads();

    // phase 3: attention (wave = 4 faces, 4 iterations); Ag aliases At (dead)
    float* Ag = At;
    int lane = tid & 63;
    int il = lane & 15, c4 = il * 4;
    for (int it = 0; it < 4; it++) {
        int fl = (tid >> 4) + it * 16;
        int face = fbase + fl;
        int b = face / FP;
        const float* fb = feaT + ((long)b * F_ALL) * 64 + c4;

        float4 sf = make_float4(Sf[fl * 65 + c4], Sf[fl * 65 + c4 + 1],
                                Sf[fl * 65 + c4 + 2], Sf[fl * 65 + c4 + 3]);
        float4 u = *(const float4*)&U[fl * 68 + c4];

        int rv = ring[face * KK + il];
        float4 nv[KK];
#pragma unroll
        for (int k = 0; k < KK; k++) {
            int rk = __shfl(rv, (lane & 48) | k, 64);
            nv[k] = *(const float4*)(fb + (long)rk * 64);
        }

        float l[KK + 1];
        l[0] = sum16(u.x * sf.x + u.y * sf.y + u.z * sf.z + u.w * sf.w) * scale;
#pragma unroll
        for (int k = 0; k < KK; k++)
            l[k + 1] = sum16(u.x * nv[k].x + u.y * nv[k].y + u.z * nv[k].z + u.w * nv[k].w) * scale;

        float m = l[0];
#pragma unroll
        for (int k = 1; k <= KK; k++) m = fmaxf(m, l[k]);
        float den = 0.f;
#pragma unroll
        for (int k = 0; k <= KK; k++) { l[k] = __expf(l[k] - m); den += l[k]; }
        float inv = 1.0f / den;

        float4 a;
        a.x = l[0] * sf.x; a.y = l[0] * sf.y; a.z = l[0] * sf.z; a.w = l[0] * sf.w;
#pragma unroll
        for (int k = 0; k < KK; k++) {
            a.x += l[k + 1] * nv[k].x;
            a.y += l[k + 1] * nv[k].y;
            a.z += l[k + 1] * nv[k].z;
            a.w += l[k + 1] * nv[k].w;
        }
        a.x *= inv; a.y *= inv; a.z *= inv; a.w *= inv;
        *(float4*)&Ag[fl * 64 + c4] = a;
        *(float4*)&ws[WS_AGG + (long)face * 64 + c4] = a;
    }
    __syncthreads();

    // phase 4: per-block gram partial over the 64 faces in LDS
    float acc[4][4];
#pragma unroll
    for (int a = 0; a < 4; a++)
#pragma unroll
        for (int b = 0; b < 4; b++) acc[a][b] = 0.f;
    float gacc[4] = {0.f, 0.f, 0.f, 0.f};
#pragma unroll 4
    for (int f = 0; f < 64; f++) {
        float4 av = *(const float4*)&Ag[f * 64 + ti * 4];
        float4 bv = *(const float4*)&Ag[f * 64 + tj * 4];
        float avv[4] = {av.x, av.y, av.z, av.w};
        float bvv[4] = {bv.x, bv.y, bv.z, bv.w};
#pragma unroll
        for (int a = 0; a < 4; a++) {
#pragma unroll
            for (int b = 0; b < 4; b++) acc[a][b] += avv[a] * bvv[b];
            gacc[a] += avv[a];
        }
    }
    float* gp = ws + WS_GP;
#pragma unroll
    for (int a = 0; a < 4; a++)
        *(float4*)&gp[(long)blockIdx.x * 4096 + (ti * 4 + a) * 64 + tj * 4] =
            make_float4(acc[a][0], acc[a][1], acc[a][2], acc[a][3]);
    if (tj == 0)
        *(float4*)&ws[WS_SAP + blockIdx.x * 64 + ti * 4] =
            make_float4(gacc[0], gacc[1], gacc[2], gacc[3]);
}

// ---------- K3: reduce gram partials (256 blocks for G, 4 for sumA) ----------
// Old version: 65 blocks, 157 serial 16KB-strided loads/thread -> 48.5us @108GB/s.
// New: 16-lane groups read one 64B sector/step, 4-way unrolled accumulators,
// 1040 waves -> latency hidden; whole gp (10.2MB, L2/LLC-hot) in ~3us.
__global__ __launch_bounds__(256) void k_gsum(float* __restrict__ ws) {
    __shared__ float red[256];
    int t = threadIdx.x;
    if (blockIdx.x < 256) {
        const float* gp = ws + WS_GP;
        int e16 = blockIdx.x * 16;          // 16-element column group
        int e = t & 15, c = t >> 4;         // 16 p-chunks
        int p0 = c * 40;
        int p1 = p0 + 40; if (p1 > NBLK) p1 = NBLK;
        float s0 = 0.f, s1 = 0.f, s2 = 0.f, s3 = 0.f;
        int p = p0;
        for (; p + 4 <= p1; p += 4) {
            s0 += gp[(long)(p + 0) * 4096 + e16 + e];
            s1 += gp[(long)(p + 1) * 4096 + e16 + e];
            s2 += gp[(long)(p + 2) * 4096 + e16 + e];
            s3 += gp[(long)(p + 3) * 4096 + e16 + e];
        }
        for (; p < p1; p++) s0 += gp[(long)p * 4096 + e16 + e];
        red[t] = (s0 + s1) + (s2 + s3);
        __syncthreads();
        if (t < 16) {
            float s = 0.f;
#pragma unroll
            for (int cc = 0; cc < 16; cc++) s += red[cc * 16 + t];
            ws[WS_G + e16 + t] = s;
        }
    } else {
        const float* sap = ws + WS_SAP;
        int bq = blockIdx.x - 256;          // 0..3
        int e = t & 63, c = t >> 6;
        int pidx = bq * 4 + c;              // global chunk 0..15
        int p0 = pidx * 40;
        int p1 = p0 + 40; if (p1 > NBLK) p1 = NBLK;
        float s0 = 0.f, s1 = 0.f, s2 = 0.f, s3 = 0.f;
        int p = p0;
        for (; p + 4 <= p1; p += 4) {
            s0 += sap[(p + 0) * 64 + e];
            s1 += sap[(p + 1) * 64 + e];
            s2 += sap[(p + 2) * 64 + e];
            s3 += sap[(p + 3) * 64 + e];
        }
        for (; p < p1; p++) s0 += sap[p * 64 + e];
        red[t] = (s0 + s1) + (s2 + s3);
        __syncthreads();
        if (t < 64) {
            float tot = red[t] + red[t + 64] + red[t + 128] + red[t + 192];
            atomicAdd(&ws[WS_SUMA + t], tot);   // 64 atomics x 4 blocks (WS_SUMA zeroed in k_pre)
        }
    }
}

// ---------- K4: BN stats -> per-o scale/shift ----------
__global__ __launch_bounds__(256) void k_stats(const float* __restrict__ Wc,
                                               const float* __restrict__ bc,
                                               const float* __restrict__ gamma,
                                               const float* __restrict__ beta,
                                               float* __restrict__ ws) {
    __shared__ float Gs[4096];
    __shared__ float gs[64];
    __shared__ float qs[256];
    int tid = threadIdx.x;
    for (int i = tid; i < 4096; i += 256) Gs[i] = ws[WS_G + i];
    if (tid < 64) gs[tid] = ws[WS_SUMA + tid];
    __syncthreads();

    int o = tid & 127, h = tid >> 7;
    float w[64];
#pragma unroll
    for (int q = 0; q < 16; q++) {
        float4 t = *(const float4*)&Wc[o * 64 + q * 4];
        w[q * 4 + 0] = t.x; w[q * 4 + 1] = t.y; w[q * 4 + 2] = t.z; w[q * 4 + 3] = t.w;
    }
    float qp = 0.f;
    for (int i = h * 32; i < h * 32 + 32; i++) {
        float t = 0.f;
#pragma unroll
        for (int j = 0; j < 64; j++) t += Gs[i * 64 + j] * w[j];
        qp += Wc[o * 64 + i] * t;
    }
    qs[tid] = qp;
    __syncthreads();
    if (h == 0) {
        const float invN = 1.0f / (float)NFACE;
        float qform = qs[o] + qs[o + 128];
        float md = 0.f;
#pragma unroll
        for (int j = 0; j < 64; j++) md += gs[j] * w[j];
        float bco = bc[o];
        float mean = md * invN + bco;
        float ey2  = (qform + 2.f * bco * md) * invN + bco * bco;
        float var  = ey2 - mean * mean;
        float sc   = gamma[o] * rsqrtf(var + 1e-5f);
        ws[WS_SC + o] = sc;
        ws[WS_SH + o] = beta[o] + (bco - mean) * sc;
    }
}

// ---------- K5: out = relu((Wc*agg)*sc + sh)  [B,O,Fp] ----------
__global__ __launch_bounds__(256) void k_out(const float* __restrict__ Wc,
                                             const float* __restrict__ ws,
                                             float* __restrict__ out) {
    __shared__ __align__(16) float WcT[64 * 132];   // [j][o]
    __shared__ __align__(16) float AgT[64 * 68];    // [j][f]
    const float* agg = ws + WS_AGG;
    int tid = threadIdx.x;
    int fbase = blockIdx.x * 64;
    for (int i = tid; i < 128 * 64; i += 256) {
        int o = i >> 6, j = i & 63;
        WcT[j * 132 + o] = Wc[i];
    }
    for (int i = tid; i < 64 * 64; i += 256) {
        int f = i >> 6, j = i & 63;
        AgT[j * 68 + f] = agg[((long)(fbase + f)) * 64 + j];
    }
    __syncthreads();

    int tx = tid & 15, ty = tid >> 4;   // tx: 4 faces, ty: 8 outputs
    float acc[8][4];
#pragma unroll
    for (int a = 0; a < 8; a++)
#pragma unroll
        for (int b = 0; b < 4; b++) acc[a][b] = 0.f;

    for (int j = 0; j < 64; j++) {
        float4 w0 = *(const float4*)&WcT[j * 132 + ty * 8];
        float4 w1 = *(const float4*)&WcT[j * 132 + ty * 8 + 4];
        float4 a0 = *(const float4*)&AgT[j * 68 + tx * 4];
        float wv[8] = {w0.x, w0.y, w0.z, w0.w, w1.x, w1.y, w1.z, w1.w};
        float av[4] = {a0.x, a0.y, a0.z, a0.w};
#pragma unroll
        for (int oi = 0; oi < 8; oi++)
#pragma unroll
            for (int fi = 0; fi < 4; fi++) acc[oi][fi] += wv[oi] * av[fi];
    }

    int fg0 = fbase + tx * 4;
    int b   = fg0 / FP;
    int fp0 = fg0 - b * FP;
#pragma unroll
    for (int oi = 0; oi < 8; oi++) {
        int o = ty * 8 + oi;
        float sc = ws[WS_SC + o];
        float sh = ws[WS_SH + o];
        float4 v;
        v.x = fmaxf(acc[oi][0] * sc + sh, 0.f);
        v.y = fmaxf(acc[oi][1] * sc + sh, 0.f);
        v.z = fmaxf(acc[oi][2] * sc + sh, 0.f);
        v.w = fmaxf(acc[oi][3] * sc + sh, 0.f);
        *(float4*)&out[((long)(b * OO + o)) * FP + fp0] = v;
    }
}

extern "C" void kernel_launch(void* const* d_in, const int* in_sizes, int n_in,
                              void* d_out, int out_size, void* d_ws, size_t ws_size,
                              hipStream_t stream) {
    const float* fea  = (const float*)d_in[0];
    const int*   ring = (const int*)d_in[1];
    const int*   pool = (const int*)d_in[2];
    const float* Wk = (const float*)d_in[4];
    const float* bk = (const float*)d_in[5];
    const float* Wq = (const float*)d_in[6];
    // bq unused: its logit contribution is constant per face -> cancels in softmax
    const float* Wc = (const float*)d_in[8];
    const float* bc = (const float*)d_in[9];
    const float* gamma = (const float*)d_in[10];
    const float* beta  = (const float*)d_in[11];

    float* out = (float*)d_out;
    float* ws  = (float*)d_ws;

    k_pre  <<<1268, 256, 0, stream>>>(fea, Wk, bk, Wq, ws);
    k_attn <<<NBLK, 256, 0, stream>>>(ring, pool, ws);
    k_gsum <<<260,  256, 0, stream>>>(ws);
    k_stats<<<1,    256, 0, stream>>>(Wc, bc, gamma, beta, ws);
    k_out  <<<NBLK, 256, 0, stream>>>(Wc, ws, out);
}